// Round 2
// baseline (454.776 us; speedup 1.0000x reference)
//
#include <hip/hip_runtime.h>

// SJLT projection: out[b, idx[d,j]] += x[b,d] * sign(d,j), * 1/sqrt(4)
// B=64, D=524288, P=8192, C=4.
//
// Model so far (R1-R7):
//  - LDS fp atomics: ~3.2 cyc/LANE (per-lane serialized) -> never use.
//  - Random 4B global stores/atomics: 64B HBM write-back EACH (no-write-
//    allocate L2). R7 measured it: fused scatter WRITE_SIZE 187 MB vs 67 MB
//    useful -> kernel store-drain bound at 1.9 TB/s, VALUBusy 5.8%.
//  - Inputs are L3-resident across iterations (FETCH 74 MB < 134 MB x).
//  - CSR(padded buckets CAP=384) + gather structure: 324us (R7).
// R8: pure vectorized transpose (no scatter, no atomics) + separate binning
// kernel with p-range partitioning: 8 ranges x 1024 p's; each range's CSR
// window is 1.5 MB < 4 MB per-XCD L2, and blockIdx&7 round-robins onto the
// 8 XCDs, so entry stores become L2 hits (write-back = useful lines only).
// Gather unroll deepened 8->16 for more row-loads in flight.

constexpr int BATCH = 64;
constexpr int DIM   = 524288;
constexpr int PROJ  = 8192;
constexpr int NENT  = DIM * 4;          // 2,097,152 entries
constexpr int CAP   = 384;              // bucket capacity: mean 256, sigma 16

// ------------------------------------------------ helpers
__device__ __forceinline__ uint32_t f2bf(float f) {   // RNE f32 -> bf16 bits
    uint32_t u = __float_as_uint(f);
    return (u + 0x7fffu + ((u >> 16) & 1u)) >> 16;
}

// ==================== R8 pass 1: pure transpose =========================
// Block owns 64 d's. Reads x tile (64b x 64d) via float4, writes xT rows
// (bf16-pair packed, scale 0.5 folded) via dwordx4 (16B/lane).
__global__ __launch_bounds__(256) void transpose_kernel(
    const float* __restrict__ x, uint32_t* __restrict__ xT)
{
    __shared__ float tile[64][65];
    const int d0 = blockIdx.x * 64;
    const int t  = threadIdx.x;

    // x tile loads: 4 x float4 per thread, all in flight together
    const int c  = t & 15;          // float4 column
    const int r0 = t >> 4;          // row 0..15
    float4 v[4];
#pragma unroll
    for (int it = 0; it < 4; ++it) {
        int b = it * 16 + r0;
        v[it] = *reinterpret_cast<const float4*>(&x[(size_t)b * DIM + d0 + 4 * c]);
    }
#pragma unroll
    for (int it = 0; it < 4; ++it) {
        int b = it * 16 + r0;
        tile[b][4 * c + 0] = v[it].x;
        tile[b][4 * c + 1] = v[it].y;
        tile[b][4 * c + 2] = v[it].z;
        tile[b][4 * c + 3] = v[it].w;
    }
    __syncthreads();

    // pack + write xT: thread -> one d row, 4 consecutive u32 (8 b-values).
    // Wave covers 8 rows x 128B contiguous each; LDS reads 2-way (free).
    const int a  = t & 7;
    const int dr = t >> 3;               // 0..31
#pragma unroll
    for (int pass = 0; pass < 2; ++pass) {
        const int dl = pass * 32 + dr;
        uint4 wv;
        uint32_t* wq = reinterpret_cast<uint32_t*>(&wv);
#pragma unroll
        for (int q = 0; q < 4; ++q) {
            const int k = 4 * a + q;     // u32 index = batch pair (2k, 2k+1)
            uint32_t lo = f2bf(tile[2 * k + 0][dl] * 0.5f);
            uint32_t hi = f2bf(tile[2 * k + 1][dl] * 0.5f);
            wq[q] = lo | (hi << 16);
        }
        *reinterpret_cast<uint4*>(&xT[(size_t)(d0 + dl) * 32 + 4 * a]) = wv;
    }
}

// ==================== R8 pass 2: L2-localized binning ===================
// 8 p-ranges of 1024. Range window = 1024*CAP*4 = 1.5 MB < 4 MB XCD L2;
// blockIdx&7 round-robins ranges onto XCDs so each L2 holds one window.
// Each range-group (256 blocks) scans ALL of idx/sgn (L3-resident) and
// keeps only entries whose p falls in its range.
__global__ __launch_bounds__(256) void bin_kernel(
    const int4* __restrict__ idx4, const int4* __restrict__ sgn4,
    uint32_t* __restrict__ cnt, uint32_t* __restrict__ entries)
{
    const int r  = blockIdx.x & 7;                       // p-range / XCD
    const int c0 = (blockIdx.x >> 3) * 256 + threadIdx.x;
#pragma unroll
    for (int i = 0; i < 8; ++i) {
        const int d  = c0 + i * 65536;
        const int4 iv = idx4[d];
        const bool m0 = (iv.x >> 10) == r;
        const bool m1 = (iv.y >> 10) == r;
        const bool m2 = (iv.z >> 10) == r;
        const bool m3 = (iv.w >> 10) == r;
        if (m0 | m1 | m2 | m3) {                         // ~41% of threads
            const int4 sv = sgn4[d];
            const uint32_t dv = (uint32_t)d << 1;
            if (m0) { uint32_t sl = atomicAdd(&cnt[iv.x], 1u);
                      entries[(uint32_t)iv.x * CAP + sl] = dv | (uint32_t)(sv.x & 1); }
            if (m1) { uint32_t sl = atomicAdd(&cnt[iv.y], 1u);
                      entries[(uint32_t)iv.y * CAP + sl] = dv | (uint32_t)(sv.y & 1); }
            if (m2) { uint32_t sl = atomicAdd(&cnt[iv.z], 1u);
                      entries[(uint32_t)iv.z * CAP + sl] = dv | (uint32_t)(sv.z & 1); }
            if (m3) { uint32_t sl = atomicAdd(&cnt[iv.w], 1u);
                      entries[(uint32_t)iv.w * CAP + sl] = dv | (uint32_t)(sv.w & 1); }
        }
    }
}

// ==================== R8 pass 3: gather (16-deep unroll) ================
// wave per p; entry stream wave-uniform -> s_load; 8 xT-row loads in flight.
__global__ __launch_bounds__(256) void gather3_kernel(
    const uint32_t* __restrict__ entries, const uint32_t* __restrict__ cnt,
    const uint32_t* __restrict__ xT, float* __restrict__ out)
{
    const int w    = threadIdx.x >> 6;
    const int lane = threadIdx.x & 63;
    const int p    = __builtin_amdgcn_readfirstlane(blockIdx.x * 4 + w);
    const uint32_t n  = __builtin_amdgcn_readfirstlane(cnt[p]);
    const uint32_t e0 = (uint32_t)p * (uint32_t)CAP;

    const int half = lane >> 5;     // 0: even entries, 1: odd entries
    const int k    = lane & 31;     // u32 index within xT row (2 batch elems)
    float acc0 = 0.f, acc1 = 0.f;

    uint32_t base = 0;
    for (; base + 16 <= n; base += 16) {     // uniform indices -> s_load
        uint32_t e16[16];
#pragma unroll
        for (int t = 0; t < 16; ++t) e16[t] = entries[e0 + base + t];
#pragma unroll
        for (int t = 0; t < 16; t += 2) {
            uint32_t sel = half ? e16[t + 1] : e16[t];
            uint32_t u = xT[(size_t)(sel >> 1) * 32 + k];   // 128B/half-wave
            u ^= (sel & 1u) ? 0u : 0x80008000u;             // s=0 -> negate pair
            acc0 += __uint_as_float(u << 16);               // b = 2k
            acc1 += __uint_as_float(u & 0xffff0000u);       // b = 2k+1
        }
    }
    for (; base + 8 <= n; base += 8) {
        uint32_t e8[8];
#pragma unroll
        for (int t = 0; t < 8; ++t) e8[t] = entries[e0 + base + t];
#pragma unroll
        for (int t = 0; t < 8; t += 2) {
            uint32_t sel = half ? e8[t + 1] : e8[t];
            uint32_t u = xT[(size_t)(sel >> 1) * 32 + k];
            u ^= (sel & 1u) ? 0u : 0x80008000u;
            acc0 += __uint_as_float(u << 16);
            acc1 += __uint_as_float(u & 0xffff0000u);
        }
    }
    for (; base < n; base += 2) {            // tail
        uint32_t eA = entries[e0 + base];
        uint32_t eB = (base + 1 < n) ? entries[e0 + base + 1] : 0u;
        uint32_t sel   = half ? eB : eA;
        bool     valid = (base + (uint32_t)half) < n;
        uint32_t u = 0u;
        if (valid) {
            u = xT[(size_t)(sel >> 1) * 32 + k];
            u ^= (sel & 1u) ? 0u : 0x80008000u;
        }
        acc0 += __uint_as_float(u << 16);
        acc1 += __uint_as_float(u & 0xffff0000u);
    }
    acc0 += __shfl_xor(acc0, 32);
    acc1 += __shfl_xor(acc1, 32);
    if (half == 0) {
        out[(size_t)(2 * k + 0) * PROJ + p] = acc0;
        out[(size_t)(2 * k + 1) * PROJ + p] = acc1;
    }
}

// ==================== R6 fallback pipeline (exact CSR), kept verbatim ====
__global__ __launch_bounds__(256) void transpose_hist_kernel(
    const float* __restrict__ x, const int4* __restrict__ idx4,
    uint32_t* __restrict__ xT, uint32_t* __restrict__ cnt)
{
    __shared__ float tile[64][65];
    const int d0   = blockIdx.x * 64;
    const int lane = threadIdx.x & 63;
    const int q    = threadIdx.x >> 6;      // wave id 0..3
#pragma unroll
    for (int r = 0; r < 16; ++r) {
        int b = r * 4 + q;
        tile[b][lane] = x[(size_t)b * DIM + d0 + lane];
    }
    if (threadIdx.x < 64) {                 // fused histogram (wave 0)
        int4 iv = idx4[d0 + threadIdx.x];
        atomicAdd(&cnt[iv.x], 1u);
        atomicAdd(&cnt[iv.y], 1u);
        atomicAdd(&cnt[iv.z], 1u);
        atomicAdd(&cnt[iv.w], 1u);
    }
    __syncthreads();
    const int k   = threadIdx.x & 31;       // u32 index in xT row
    const int dl0 = threadIdx.x >> 5;       // 0..7
#pragma unroll
    for (int pass = 0; pass < 8; ++pass) {
        int dl = pass * 8 + dl0;
        uint32_t lo = f2bf(tile[2 * k + 0][dl] * 0.5f);
        uint32_t hi = f2bf(tile[2 * k + 1][dl] * 0.5f);
        xT[(size_t)(d0 + dl) * 32 + k] = lo | (hi << 16);
    }
}

__global__ __launch_bounds__(256) void scan_kernel(
    const uint32_t* __restrict__ cnt, uint32_t* __restrict__ cur)
{
    __shared__ uint32_t wsum[4];
    const int t    = threadIdx.x;
    const int lane = t & 63;
    uint32_t c[32];
    uint32_t s = 0;
#pragma unroll
    for (int i = 0; i < 32; ++i) { c[i] = cnt[t * 32 + i]; s += c[i]; }
    uint32_t v = s;                          // inclusive scan of thread sums
#pragma unroll
    for (int off = 1; off < 64; off <<= 1) {
        uint32_t u = __shfl_up(v, off);
        if (lane >= off) v += u;
    }
    if (lane == 63) wsum[t >> 6] = v;
    __syncthreads();
    uint32_t wb = 0;
    for (int w0 = 0; w0 < (t >> 6); ++w0) wb += wsum[w0];
    uint32_t base = wb + v - s;              // exclusive base for this thread
#pragma unroll
    for (int i = 0; i < 32; ++i) { cur[t * 32 + i] = base; base += c[i]; }
}

__global__ __launch_bounds__(256) void scatter_kernel(
    const int4* __restrict__ idx4, const int4* __restrict__ sgn4,
    uint32_t* __restrict__ cur, uint32_t* __restrict__ entries)
{
    int d = blockIdx.x * 256 + threadIdx.x;
    int4 iv = idx4[d];
    int4 sv = sgn4[d];
    const uint32_t dv = (uint32_t)d << 1;
    uint32_t slot;
    slot = atomicAdd(&cur[iv.x], 1u); entries[slot] = dv | (uint32_t)(sv.x & 1);
    slot = atomicAdd(&cur[iv.y], 1u); entries[slot] = dv | (uint32_t)(sv.y & 1);
    slot = atomicAdd(&cur[iv.z], 1u); entries[slot] = dv | (uint32_t)(sv.z & 1);
    slot = atomicAdd(&cur[iv.w], 1u); entries[slot] = dv | (uint32_t)(sv.w & 1);
}

__global__ __launch_bounds__(256) void gather_kernel(
    const uint32_t* __restrict__ entries, const uint32_t* __restrict__ cnt,
    const uint32_t* __restrict__ endp, const uint32_t* __restrict__ xT,
    float* __restrict__ out)
{
    const int w    = threadIdx.x >> 6;
    const int lane = threadIdx.x & 63;
    const int p    = __builtin_amdgcn_readfirstlane(blockIdx.x * 4 + w);
    const uint32_t n  = __builtin_amdgcn_readfirstlane(cnt[p]);
    const uint32_t e0 = __builtin_amdgcn_readfirstlane(endp[p] - n);

    const int half = lane >> 5;
    const int k    = lane & 31;
    float acc0 = 0.f, acc1 = 0.f;

    uint32_t base = 0;
    for (; base + 8 <= n; base += 8) {
        uint32_t e8[8];
#pragma unroll
        for (int t = 0; t < 8; ++t) e8[t] = entries[e0 + base + t];
#pragma unroll
        for (int t = 0; t < 8; t += 2) {
            uint32_t sel = half ? e8[t + 1] : e8[t];
            uint32_t u = xT[(size_t)(sel >> 1) * 32 + k];
            u ^= (sel & 1u) ? 0u : 0x80008000u;
            acc0 += __uint_as_float(u << 16);
            acc1 += __uint_as_float(u & 0xffff0000u);
        }
    }
    for (; base < n; base += 2) {
        uint32_t eA = entries[e0 + base];
        uint32_t eB = (base + 1 < n) ? entries[e0 + base + 1] : 0u;
        uint32_t sel   = half ? eB : eA;
        bool     valid = (base + (uint32_t)half) < n;
        uint32_t u = 0u;
        if (valid) {
            u = xT[(size_t)(sel >> 1) * 32 + k];
            u ^= (sel & 1u) ? 0u : 0x80008000u;
        }
        acc0 += __uint_as_float(u << 16);
        acc1 += __uint_as_float(u & 0xffff0000u);
    }
    acc0 += __shfl_xor(acc0, 32);
    acc1 += __shfl_xor(acc1, 32);
    if (half == 0) {
        out[(size_t)(2 * k + 0) * PROJ + p] = acc0;
        out[(size_t)(2 * k + 1) * PROJ + p] = acc1;
    }
}

// ------------------------------------------------- fallback (R3 scatter)
__device__ __forceinline__ void lds_fadd(uint32_t byte_addr, float v) {
    asm volatile("ds_add_f32 %0, %1" :: "v"(byte_addr), "v"(v) : "memory");
}
__device__ __forceinline__ void lds_fadd_off32k(uint32_t byte_addr, float v) {
    asm volatile("ds_add_f32 %0, %1 offset:32768" :: "v"(byte_addr), "v"(v) : "memory");
}

__global__ __launch_bounds__(1024) void sjlt_scatter(
    const float* __restrict__ x, const int4* __restrict__ idx4,
    const int4* __restrict__ sgn4, float* __restrict__ out)
{
    __shared__ float acc[4 * PROJ];
    for (int i = threadIdx.x; i < 4 * PROJ; i += 1024) acc[i] = 0.0f;
    __syncthreads();
    const int row0 = blockIdx.y * 4;
    const int dbeg = blockIdx.x * (DIM / 16);
    const uint32_t accBase = (uint32_t)(uintptr_t)(&acc[0]);
    const float* xr0 = x + (size_t)(row0 + 0) * DIM;
    const float* xr1 = x + (size_t)(row0 + 1) * DIM;
    const float* xr2 = x + (size_t)(row0 + 2) * DIM;
    const float* xr3 = x + (size_t)(row0 + 3) * DIM;
    for (int d = dbeg + (int)threadIdx.x; d < dbeg + DIM / 16; d += 1024) {
        const int4 iv = idx4[d];
        const int4 sv = sgn4[d];
        const uint32_t u0 = __float_as_uint(xr0[d]);
        const uint32_t u1 = __float_as_uint(xr1[d]);
        const uint32_t u2 = __float_as_uint(xr2[d]);
        const uint32_t u3 = __float_as_uint(xr3[d]);
        const int p[4] = {iv.x, iv.y, iv.z, iv.w};
        const int s[4] = {sv.x, sv.y, sv.z, sv.w};
#pragma unroll
        for (int j = 0; j < 4; ++j) {
            const uint32_t flip = (uint32_t)(s[j] ^ 1) << 31;
            const uint32_t a01  = accBase + ((uint32_t)p[j] << 2);
            const uint32_t a23  = a01 + 2u * 32768u;
            lds_fadd        (a01, __uint_as_float(u0 ^ flip));
            lds_fadd_off32k (a01, __uint_as_float(u1 ^ flip));
            lds_fadd        (a23, __uint_as_float(u2 ^ flip));
            lds_fadd_off32k (a23, __uint_as_float(u3 ^ flip));
        }
    }
    __syncthreads();
    for (int i = threadIdx.x; i < 4 * PROJ; i += 1024) {
        const int r  = i >> 13;
        const int pp = i & (PROJ - 1);
        unsafeAtomicAdd(&out[(size_t)(row0 + r) * PROJ + pp], acc[i] * 0.5f);
    }
}

// --------------------------------------------------------------- launch
extern "C" void kernel_launch(void* const* d_in, const int* in_sizes, int n_in,
                              void* d_out, int out_size, void* d_ws, size_t ws_size,
                              hipStream_t stream) {
    const float* x   = (const float*)d_in[0];
    const int4*  idx = (const int4*) d_in[1];
    const int4*  sgn = (const int4*) d_in[2];
    float*       out = (float*)d_out;

    // R8 layout: cnt[PROJ] | entries[PROJ*CAP] | xT[DIM*32]  = 79,724,544 B
    const size_t need_new = ((size_t)PROJ + (size_t)PROJ * CAP + (size_t)DIM * 32) * 4;
    // R6 layout: cnt | cur | entries[NENT] | xT               = 75,563,008 B
    const size_t need_old = ((size_t)PROJ + PROJ + NENT + (size_t)DIM * 32) * 4;

    if (ws_size >= need_new) {
        uint32_t* cnt     = (uint32_t*)d_ws;
        uint32_t* entries = cnt + PROJ;
        uint32_t* xT      = entries + (size_t)PROJ * CAP;

        hipMemsetAsync(cnt, 0, PROJ * sizeof(uint32_t), stream);
        bin_kernel      <<<2048,     256, 0, stream>>>(idx, sgn, cnt, entries);
        transpose_kernel<<<DIM / 64, 256, 0, stream>>>(x, xT);
        gather3_kernel  <<<PROJ / 4, 256, 0, stream>>>(entries, cnt, xT, out);
    } else if (ws_size >= need_old) {
        uint32_t* cnt     = (uint32_t*)d_ws;
        uint32_t* cur     = cnt + PROJ;
        uint32_t* entries = cur + PROJ;
        uint32_t* xT      = entries + NENT;

        hipMemsetAsync(cnt, 0, PROJ * sizeof(uint32_t), stream);
        hipMemsetAsync(entries, 0, (size_t)NENT * sizeof(uint32_t), stream);
        transpose_hist_kernel<<<DIM / 64,  256, 0, stream>>>(x, idx, xT, cnt);
        scan_kernel          <<<1,         256, 0, stream>>>(cnt, cur);
        scatter_kernel       <<<DIM / 256, 256, 0, stream>>>(idx, sgn, cur, entries);
        gather_kernel        <<<PROJ / 4,  256, 0, stream>>>(entries, cnt, cur, xT, out);
    } else {
        // ws too small: R3 LDS-scatter path (passes at ~830 us)
        hipMemsetAsync(d_out, 0, (size_t)out_size * sizeof(float), stream);
        dim3 grid(16, 16);
        sjlt_scatter<<<grid, 1024, 0, stream>>>(x, idx, sgn, out);
    }
}

// Round 3
// 285.839 us; speedup vs baseline: 1.5910x; 1.5910x over previous
//
#include <hip/hip_runtime.h>

// SJLT projection: out[b, idx[d,j]] += x[b,d] * sign(d,j), * 1/sqrt(4)
// B=64, D=524288, P=8192, C=4.
//
// Model so far (R1-R8):
//  - LDS fp atomics: ~3.2 cyc/LANE (per-lane serialized) -> never use.
//  - Random 4B global stores: 64B HBM write-back EACH. L2 is NO-WRITE-
//    ALLOCATE on store miss: R8 proved spatial partitioning of the store
//    window does NOT help (bin_kernel WRITE still 73 MB, 152us, regression).
//    Only chance: make the line RESIDENT before the store (pretouch) ->
//    R9 tests memset-pretouch directly on the fused kernel.
//  - Inputs L3-resident across iterations (FETCH 74 MB < 134 MB x).
//  - R7 (fused transpose+scatter 101us + gather ~95us) = 324us, best.
// R9: R7 structure + entries memset-pretouch + gather rework:
//   gather4: 16 p per 1024-thread block, LDS-staged output -> full-line
//   64B out writes (2 MB instead of ~33 MB inflated), A/B double-buffered
//   entry stream (64B granules) to overlap entry loads with xT row loads.

constexpr int BATCH = 64;
constexpr int DIM   = 524288;
constexpr int PROJ  = 8192;
constexpr int NENT  = DIM * 4;          // 2,097,152 entries
constexpr int CAP   = 384;              // bucket capacity: mean 256, sigma 16

// ------------------------------------------------ helpers
__device__ __forceinline__ uint32_t f2bf(float f) {   // RNE f32 -> bf16 bits
    uint32_t u = __float_as_uint(f);
    return (u + 0x7fffu + ((u >> 16) & 1u)) >> 16;
}

// ==================== pass 1: fused transpose + padded-bucket scatter ===
// Block owns 64 d's. Reads x tile (64b x 64d) via float4, writes xT rows
// (bf16-pair packed, scale 0.5 folded) via dwordx4. Each thread also owns
// one (d,j) entry: slot = atomicAdd(cnt[p]), entries[p*CAP+slot] = d<<1|s.
__global__ __launch_bounds__(256) void fused_tx_scatter(
    const float* __restrict__ x, const int* __restrict__ idx,
    const int* __restrict__ sgn, uint32_t* __restrict__ cnt,
    uint32_t* __restrict__ entries, uint32_t* __restrict__ xT)
{
    __shared__ float tile[64][65];
    const int d0 = blockIdx.x * 64;
    const int t  = threadIdx.x;

    // scatter operand loads: e = 4*d0 + t covers this block's 256 entries
    const int e = (d0 << 2) + t;
    const int p = idx[e];
    const int s = sgn[e] & 1;

    // x tile loads: 4 x float4 per thread, all in flight together
    const int c  = t & 15;          // float4 column
    const int r0 = t >> 4;          // row 0..15
    float4 v[4];
#pragma unroll
    for (int it = 0; it < 4; ++it) {
        int b = it * 16 + r0;
        v[it] = *reinterpret_cast<const float4*>(&x[(size_t)b * DIM + d0 + 4 * c]);
    }

    // CSR entry: atomic slot + random 4B store (pretouched region -> L2 hit?)
    {
        uint32_t dv   = ((uint32_t)(d0 + (t >> 2)) << 1) | (uint32_t)s;
        uint32_t slot = atomicAdd(&cnt[p], 1u);
        entries[(uint32_t)p * (uint32_t)CAP + slot] = dv;
    }

#pragma unroll
    for (int it = 0; it < 4; ++it) {
        int b = it * 16 + r0;
        tile[b][4 * c + 0] = v[it].x;
        tile[b][4 * c + 1] = v[it].y;
        tile[b][4 * c + 2] = v[it].z;
        tile[b][4 * c + 3] = v[it].w;
    }
    __syncthreads();

    // pack + write xT: thread -> one d row, 4 consecutive u32 (8 b-values)
    const int a  = t & 7;
    const int dr = t >> 3;               // 0..31
#pragma unroll
    for (int pass = 0; pass < 2; ++pass) {
        const int dl = pass * 32 + dr;
        uint4 wv;
        uint32_t* wq = reinterpret_cast<uint32_t*>(&wv);
#pragma unroll
        for (int q = 0; q < 4; ++q) {
            const int k = 4 * a + q;     // u32 index = batch pair (2k, 2k+1)
            uint32_t lo = f2bf(tile[2 * k + 0][dl] * 0.5f);
            uint32_t hi = f2bf(tile[2 * k + 1][dl] * 0.5f);
            wq[q] = lo | (hi << 16);
        }
        *reinterpret_cast<uint4*>(&xT[(size_t)(d0 + dl) * 32 + 4 * a]) = wv;
    }
}

// ==================== pass 2: gather =====================================
// 512 blocks x 1024 threads; wave w handles p = blockIdx*16 + w.
// Entry stream wave-uniform -> scalar loads; A/B double-buffer (8 = one
// 64B line) overlaps next entry-line load with current xT row loads.
// Output staged in LDS then written as 64 full 64B lines (no inflation).
__device__ __forceinline__ void proc8(const uint32_t* __restrict__ e,
    const uint32_t* __restrict__ xT, int half, int k,
    float& acc0, float& acc1)
{
#pragma unroll
    for (int t = 0; t < 8; t += 2) {
        uint32_t sel = half ? e[t + 1] : e[t];
        uint32_t u = xT[(size_t)(sel >> 1) * 32 + k];   // 128B/half-wave
        u ^= (sel & 1u) ? 0u : 0x80008000u;             // s=0 -> negate pair
        acc0 += __uint_as_float(u << 16);               // b = 2k
        acc1 += __uint_as_float(u & 0xffff0000u);       // b = 2k+1
    }
}

__global__ __launch_bounds__(1024) void gather4_kernel(
    const uint32_t* __restrict__ entries, const uint32_t* __restrict__ cnt,
    const uint32_t* __restrict__ xT, float* __restrict__ out)
{
    __shared__ float obuf[64][17];       // [b][p_local], +1 pad: bank (2k+w)%32
    const int w    = threadIdx.x >> 6;   // 0..15
    const int lane = threadIdx.x & 63;
    const int p    = __builtin_amdgcn_readfirstlane(blockIdx.x * 16 + w);
    const uint32_t n  = __builtin_amdgcn_readfirstlane(cnt[p]);
    const uint32_t e0 = (uint32_t)p * (uint32_t)CAP;

    const int half = lane >> 5;     // 0: even entries, 1: odd entries
    const int k    = lane & 31;     // u32 index within xT row (2 batch elems)
    float acc0 = 0.f, acc1 = 0.f;

    uint32_t A[8], B[8];
    uint32_t base = 0;
    if (n >= 8) {
#pragma unroll
        for (int t = 0; t < 8; ++t) A[t] = entries[e0 + t];
    }
    for (; base + 24 <= n; base += 16) {
#pragma unroll
        for (int t = 0; t < 8; ++t) B[t] = entries[e0 + base + 8 + t];
        proc8(A, xT, half, k, acc0, acc1);
#pragma unroll
        for (int t = 0; t < 8; ++t) A[t] = entries[e0 + base + 16 + t];
        proc8(B, xT, half, k, acc0, acc1);
    }
    if (base + 16 <= n) {
#pragma unroll
        for (int t = 0; t < 8; ++t) B[t] = entries[e0 + base + 8 + t];
        proc8(A, xT, half, k, acc0, acc1);
        proc8(B, xT, half, k, acc0, acc1);
        base += 16;
    } else if (base + 8 <= n) {
        proc8(A, xT, half, k, acc0, acc1);
        base += 8;
    }
    for (; base < n; base += 2) {            // tail (<8 entries)
        uint32_t eA = entries[e0 + base];
        uint32_t eB = (base + 1 < n) ? entries[e0 + base + 1] : 0u;
        uint32_t sel   = half ? eB : eA;
        bool     valid = (base + (uint32_t)half) < n;
        uint32_t u = 0u;
        if (valid) {
            u = xT[(size_t)(sel >> 1) * 32 + k];
            u ^= (sel & 1u) ? 0u : 0x80008000u;
        }
        acc0 += __uint_as_float(u << 16);
        acc1 += __uint_as_float(u & 0xffff0000u);
    }
    acc0 += __shfl_xor(acc0, 32);
    acc1 += __shfl_xor(acc1, 32);
    if (half == 0) {
        obuf[2 * k + 0][w] = acc0;
        obuf[2 * k + 1][w] = acc1;
    }
    __syncthreads();
    // write out: 64 rows x 16 p = 64B full lines; 256 threads, 16B each
    const int t = threadIdx.x;
    if (t < 256) {
        const int b = t >> 2, q = t & 3;
        float4 v;
        v.x = obuf[b][4 * q + 0];
        v.y = obuf[b][4 * q + 1];
        v.z = obuf[b][4 * q + 2];
        v.w = obuf[b][4 * q + 3];
        *reinterpret_cast<float4*>(&out[(size_t)b * PROJ + blockIdx.x * 16 + 4 * q]) = v;
    }
}

// ==================== R6 fallback pipeline (exact CSR), kept verbatim ====
__global__ __launch_bounds__(256) void transpose_hist_kernel(
    const float* __restrict__ x, const int4* __restrict__ idx4,
    uint32_t* __restrict__ xT, uint32_t* __restrict__ cnt)
{
    __shared__ float tile[64][65];
    const int d0   = blockIdx.x * 64;
    const int lane = threadIdx.x & 63;
    const int q    = threadIdx.x >> 6;      // wave id 0..3
#pragma unroll
    for (int r = 0; r < 16; ++r) {
        int b = r * 4 + q;
        tile[b][lane] = x[(size_t)b * DIM + d0 + lane];
    }
    if (threadIdx.x < 64) {                 // fused histogram (wave 0)
        int4 iv = idx4[d0 + threadIdx.x];
        atomicAdd(&cnt[iv.x], 1u);
        atomicAdd(&cnt[iv.y], 1u);
        atomicAdd(&cnt[iv.z], 1u);
        atomicAdd(&cnt[iv.w], 1u);
    }
    __syncthreads();
    const int k   = threadIdx.x & 31;       // u32 index in xT row
    const int dl0 = threadIdx.x >> 5;       // 0..7
#pragma unroll
    for (int pass = 0; pass < 8; ++pass) {
        int dl = pass * 8 + dl0;
        uint32_t lo = f2bf(tile[2 * k + 0][dl] * 0.5f);
        uint32_t hi = f2bf(tile[2 * k + 1][dl] * 0.5f);
        xT[(size_t)(d0 + dl) * 32 + k] = lo | (hi << 16);
    }
}

__global__ __launch_bounds__(256) void scan_kernel(
    const uint32_t* __restrict__ cnt, uint32_t* __restrict__ cur)
{
    __shared__ uint32_t wsum[4];
    const int t    = threadIdx.x;
    const int lane = t & 63;
    uint32_t c[32];
    uint32_t s = 0;
#pragma unroll
    for (int i = 0; i < 32; ++i) { c[i] = cnt[t * 32 + i]; s += c[i]; }
    uint32_t v = s;                          // inclusive scan of thread sums
#pragma unroll
    for (int off = 1; off < 64; off <<= 1) {
        uint32_t u = __shfl_up(v, off);
        if (lane >= off) v += u;
    }
    if (lane == 63) wsum[t >> 6] = v;
    __syncthreads();
    uint32_t wb = 0;
    for (int w0 = 0; w0 < (t >> 6); ++w0) wb += wsum[w0];
    uint32_t base = wb + v - s;              // exclusive base for this thread
#pragma unroll
    for (int i = 0; i < 32; ++i) { cur[t * 32 + i] = base; base += c[i]; }
}

__global__ __launch_bounds__(256) void scatter_kernel(
    const int4* __restrict__ idx4, const int4* __restrict__ sgn4,
    uint32_t* __restrict__ cur, uint32_t* __restrict__ entries)
{
    int d = blockIdx.x * 256 + threadIdx.x;
    int4 iv = idx4[d];
    int4 sv = sgn4[d];
    const uint32_t dv = (uint32_t)d << 1;
    uint32_t slot;
    slot = atomicAdd(&cur[iv.x], 1u); entries[slot] = dv | (uint32_t)(sv.x & 1);
    slot = atomicAdd(&cur[iv.y], 1u); entries[slot] = dv | (uint32_t)(sv.y & 1);
    slot = atomicAdd(&cur[iv.z], 1u); entries[slot] = dv | (uint32_t)(sv.z & 1);
    slot = atomicAdd(&cur[iv.w], 1u); entries[slot] = dv | (uint32_t)(sv.w & 1);
}

__global__ __launch_bounds__(256) void gather_kernel(
    const uint32_t* __restrict__ entries, const uint32_t* __restrict__ cnt,
    const uint32_t* __restrict__ endp, const uint32_t* __restrict__ xT,
    float* __restrict__ out)
{
    const int w    = threadIdx.x >> 6;
    const int lane = threadIdx.x & 63;
    const int p    = __builtin_amdgcn_readfirstlane(blockIdx.x * 4 + w);
    const uint32_t n  = __builtin_amdgcn_readfirstlane(cnt[p]);
    const uint32_t e0 = __builtin_amdgcn_readfirstlane(endp[p] - n);

    const int half = lane >> 5;
    const int k    = lane & 31;
    float acc0 = 0.f, acc1 = 0.f;

    uint32_t base = 0;
    for (; base + 8 <= n; base += 8) {
        uint32_t e8[8];
#pragma unroll
        for (int t = 0; t < 8; ++t) e8[t] = entries[e0 + base + t];
#pragma unroll
        for (int t = 0; t < 8; t += 2) {
            uint32_t sel = half ? e8[t + 1] : e8[t];
            uint32_t u = xT[(size_t)(sel >> 1) * 32 + k];
            u ^= (sel & 1u) ? 0u : 0x80008000u;
            acc0 += __uint_as_float(u << 16);
            acc1 += __uint_as_float(u & 0xffff0000u);
        }
    }
    for (; base < n; base += 2) {
        uint32_t eA = entries[e0 + base];
        uint32_t eB = (base + 1 < n) ? entries[e0 + base + 1] : 0u;
        uint32_t sel   = half ? eB : eA;
        bool     valid = (base + (uint32_t)half) < n;
        uint32_t u = 0u;
        if (valid) {
            u = xT[(size_t)(sel >> 1) * 32 + k];
            u ^= (sel & 1u) ? 0u : 0x80008000u;
        }
        acc0 += __uint_as_float(u << 16);
        acc1 += __uint_as_float(u & 0xffff0000u);
    }
    acc0 += __shfl_xor(acc0, 32);
    acc1 += __shfl_xor(acc1, 32);
    if (half == 0) {
        out[(size_t)(2 * k + 0) * PROJ + p] = acc0;
        out[(size_t)(2 * k + 1) * PROJ + p] = acc1;
    }
}

// ------------------------------------------------- fallback (R3 scatter)
__device__ __forceinline__ void lds_fadd(uint32_t byte_addr, float v) {
    asm volatile("ds_add_f32 %0, %1" :: "v"(byte_addr), "v"(v) : "memory");
}
__device__ __forceinline__ void lds_fadd_off32k(uint32_t byte_addr, float v) {
    asm volatile("ds_add_f32 %0, %1 offset:32768" :: "v"(byte_addr), "v"(v) : "memory");
}

__global__ __launch_bounds__(1024) void sjlt_scatter(
    const float* __restrict__ x, const int4* __restrict__ idx4,
    const int4* __restrict__ sgn4, float* __restrict__ out)
{
    __shared__ float acc[4 * PROJ];
    for (int i = threadIdx.x; i < 4 * PROJ; i += 1024) acc[i] = 0.0f;
    __syncthreads();
    const int row0 = blockIdx.y * 4;
    const int dbeg = blockIdx.x * (DIM / 16);
    const uint32_t accBase = (uint32_t)(uintptr_t)(&acc[0]);
    const float* xr0 = x + (size_t)(row0 + 0) * DIM;
    const float* xr1 = x + (size_t)(row0 + 1) * DIM;
    const float* xr2 = x + (size_t)(row0 + 2) * DIM;
    const float* xr3 = x + (size_t)(row0 + 3) * DIM;
    for (int d = dbeg + (int)threadIdx.x; d < dbeg + DIM / 16; d += 1024) {
        const int4 iv = idx4[d];
        const int4 sv = sgn4[d];
        const uint32_t u0 = __float_as_uint(xr0[d]);
        const uint32_t u1 = __float_as_uint(xr1[d]);
        const uint32_t u2 = __float_as_uint(xr2[d]);
        const uint32_t u3 = __float_as_uint(xr3[d]);
        const int p[4] = {iv.x, iv.y, iv.z, iv.w};
        const int s[4] = {sv.x, sv.y, sv.z, sv.w};
#pragma unroll
        for (int j = 0; j < 4; ++j) {
            const uint32_t flip = (uint32_t)(s[j] ^ 1) << 31;
            const uint32_t a01  = accBase + ((uint32_t)p[j] << 2);
            const uint32_t a23  = a01 + 2u * 32768u;
            lds_fadd        (a01, __uint_as_float(u0 ^ flip));
            lds_fadd_off32k (a01, __uint_as_float(u1 ^ flip));
            lds_fadd        (a23, __uint_as_float(u2 ^ flip));
            lds_fadd_off32k (a23, __uint_as_float(u3 ^ flip));
        }
    }
    __syncthreads();
    for (int i = threadIdx.x; i < 4 * PROJ; i += 1024) {
        const int r  = i >> 13;
        const int pp = i & (PROJ - 1);
        unsafeAtomicAdd(&out[(size_t)(row0 + r) * PROJ + pp], acc[i] * 0.5f);
    }
}

// --------------------------------------------------------------- launch
extern "C" void kernel_launch(void* const* d_in, const int* in_sizes, int n_in,
                              void* d_out, int out_size, void* d_ws, size_t ws_size,
                              hipStream_t stream) {
    const float* x   = (const float*)d_in[0];
    const int4*  idx = (const int4*) d_in[1];
    const int4*  sgn = (const int4*) d_in[2];
    float*       out = (float*)d_out;

    // R9 layout: cnt[PROJ] | entries[PROJ*CAP] | xT[DIM*32]  = 79,724,544 B
    const size_t need_new = ((size_t)PROJ + (size_t)PROJ * CAP + (size_t)DIM * 32) * 4;
    // R6 layout: cnt | cur | entries[NENT] | xT               = 75,563,008 B
    const size_t need_old = ((size_t)PROJ + PROJ + NENT + (size_t)DIM * 32) * 4;

    if (ws_size >= need_new) {
        uint32_t* cnt     = (uint32_t*)d_ws;
        uint32_t* entries = cnt + PROJ;
        uint32_t* xT      = entries + (size_t)PROJ * CAP;

        hipMemsetAsync(cnt, 0, PROJ * sizeof(uint32_t), stream);
        // pretouch: full-line memset may leave entries lines L2-resident so
        // the fused kernel's 4B entry stores hit (no 64B/store drain)
        hipMemsetAsync(entries, 0, (size_t)PROJ * CAP * sizeof(uint32_t), stream);
        fused_tx_scatter<<<DIM / 64, 256, 0, stream>>>(
            x, (const int*)idx, (const int*)sgn, cnt, entries, xT);
        gather4_kernel<<<PROJ / 16, 1024, 0, stream>>>(entries, cnt, xT, out);
    } else if (ws_size >= need_old) {
        uint32_t* cnt     = (uint32_t*)d_ws;
        uint32_t* cur     = cnt + PROJ;
        uint32_t* entries = cur + PROJ;
        uint32_t* xT      = entries + NENT;

        hipMemsetAsync(cnt, 0, PROJ * sizeof(uint32_t), stream);
        hipMemsetAsync(entries, 0, (size_t)NENT * sizeof(uint32_t), stream);
        transpose_hist_kernel<<<DIM / 64,  256, 0, stream>>>(x, idx, xT, cnt);
        scan_kernel          <<<1,         256, 0, stream>>>(cnt, cur);
        scatter_kernel       <<<DIM / 256, 256, 0, stream>>>(idx, sgn, cur, entries);
        gather_kernel        <<<PROJ / 4,  256, 0, stream>>>(entries, cnt, cur, xT, out);
    } else {
        // ws too small: R3 LDS-scatter path (passes at ~830 us)
        hipMemsetAsync(d_out, 0, (size_t)out_size * sizeof(float), stream);
        dim3 grid(16, 16);
        sjlt_scatter<<<grid, 1024, 0, stream>>>(x, idx, sgn, out);
    }
}